// Round 9
// baseline (516.653 us; speedup 1.0000x reference)
//
#include <hip/hip_runtime.h>
#include <stdint.h>

// Problem constants
#define B_   4
#define NQ_  2048
#define SK_  2048
#define H_   16
#define HS_  1024   // HSIZE = OSIZE = ISIZE
#define D_   64
#define TOKc ((size_t)B_ * NQ_ * HS_)   // 8388608
#define WEc  ((size_t)HS_ * HS_)        // 1048576

typedef __attribute__((ext_vector_type(8))) short bf16x8;          // MFMA A/B frag (4 VGPR)
typedef __attribute__((ext_vector_type(4))) float f32x4;           // MFMA C/D frag
typedef __attribute__((ext_vector_type(2))) float f32x2;           // packed-f32 pair
typedef __attribute__((ext_vector_type(8))) unsigned short u16x8;  // 8 bf16 = 16B
typedef __attribute__((ext_vector_type(4))) int i32x4;             // 4 int32 = 16B

#define DEVI __device__ __forceinline__

// fp32 -> bf16, round-half-up (1 v_add)
DEVI unsigned short f2bf_hu(float f) {
  union { float f; unsigned int i; } x; x.f = f;
  return (unsigned short)((x.i + 0x8000u) >> 16);
}
// two fp32 -> packed bf16x2: 2 v_add + 1 v_perm
DEVI unsigned int pack2(float a, float b) {
  union { float f; unsigned int i; } x, y; x.f = a; y.f = b;
  return __builtin_amdgcn_perm(y.i + 0x8000u, x.i + 0x8000u, 0x07060302u);
}
DEVI u16x8 cvt8(f32x4 lo, f32x4 hi) {  // 8 fp32 -> 8 bf16
  union { u16x8 s; unsigned int w[4]; } r;
  r.w[0] = pack2(lo[0], lo[1]);
  r.w[1] = pack2(lo[2], lo[3]);
  r.w[2] = pack2(hi[0], hi[1]);
  r.w[3] = pack2(hi[2], hi[3]);
  return r.s;
}
DEVI void async16(void* lds, const void* g) {  // 16B global->LDS DMA (dest = lane-contiguous)
  __builtin_amdgcn_global_load_lds(
      (const __attribute__((address_space(1))) unsigned int*)g,
      (__attribute__((address_space(3))) unsigned int*)lds, 16, 0, 0);
}

// ---- packed-f32 VOP3P helpers ----
DEVI f32x2 pkfma(f32x2 a, f32x2 b, f32x2 c) {
  f32x2 d;
  asm("v_pk_fma_f32 %0, %1, %2, %3" : "=v"(d) : "v"(a), "v"(b), "v"(c));
  return d;
}
DEVI f32x2 pkmul(f32x2 a, f32x2 b) {
  f32x2 d;
  asm("v_pk_mul_f32 %0, %1, %2" : "=v"(d) : "v"(a), "v"(b));
  return d;
}
DEVI f32x2 pkadd(f32x2 a, f32x2 b) {
  f32x2 d;
  asm("v_pk_add_f32 %0, %1, %2" : "=v"(d) : "v"(a), "v"(b));
  return d;
}
// 2 f32 -> 1 u32 of 2 bf16 (RNE)
DEVI unsigned int cvtpk_bf16(float lo, float hi) {
  unsigned int r;
  asm("v_cvt_pk_bf16_f32 %0, %1, %2" : "=v"(r) : "v"(lo), "v"(hi));
  return r;
}
// keep-mask: bit OFF of nb (inverted mask) == 1 -> keep x, else 0.
template <int OFF>
DEVI float keepf(float x, unsigned int nb) {
  int k;
  asm("v_bfe_i32 %0, %1, %2, 1" : "=v"(k) : "v"(nb), "i"(OFF));
  union { float f; int i; } u; u.f = x; u.i &= k;
  return u.f;
}

// LDS swizzle for [R][64] bf16 tiles (128B rows): XOR 16B-slot with row&7.
#define SWZB(row, colb) ((((row) * 128) + (colb)) ^ (((row) & 7) << 4))

// ---------------------------------------------------------------------------
// Prep kernels
// ---------------------------------------------------------------------------
__global__ __launch_bounds__(256)
void cvt_prep(const float* __restrict__ a, unsigned short* __restrict__ ab,
              const float* __restrict__ wsrc, unsigned short* __restrict__ wdst,
              int naBlocks) {
  const int bi = blockIdx.x;
  const float* s; unsigned short* d; size_t base;
  if (bi < naBlocks) { s = a;    d = ab;   base = (size_t)bi * 2048; }
  else               { s = wsrc; d = wdst; base = (size_t)(bi - naBlocks) * 2048; }
  const size_t o = base + (size_t)threadIdx.x * 8;
  f32x4 lo = *(const f32x4*)(s + o);
  f32x4 hi = *(const f32x4*)(s + o + 4);
  *(u16x8*)(d + o) = cvt8(lo, hi);
}

// Fused: iQ,iK,iV -> ACT; Wq..Wo -> WALL; mask -> bitmask. One launch.
// grid = 12288 (acts) + 2048 (weights) + 65536 (mask) = 79872 blocks.
__global__ __launch_bounds__(256)
void cvt_pack(const float* __restrict__ iQ, const float* __restrict__ iK,
              const float* __restrict__ iV, const float* __restrict__ Wq,
              const float* __restrict__ Wk, const float* __restrict__ Wv,
              const float* __restrict__ Wo, const int* __restrict__ m,
              unsigned short* __restrict__ ACT, unsigned short* __restrict__ WALL,
              unsigned long long* __restrict__ bits) {
  const int bi = blockIdx.x;
  if (bi >= 14336) {  // mask bit-pack
    const size_t tid = (size_t)(bi - 14336) * 256 + threadIdx.x;
    const unsigned long long bal = __ballot(m[tid] != 0);
    if ((threadIdx.x & 63) == 0) bits[tid >> 6] = bal;
    return;
  }
  const float* s; unsigned short* d; size_t base;
  if (bi < 12288) {
    const int which = bi >> 12;  // /4096
    s = (which == 0) ? iQ : (which == 1) ? iK : iV;
    d = ACT + (size_t)which * TOKc;
    base = (size_t)(bi & 4095) * 2048;
  } else {
    const int wi = (bi - 12288) >> 9;  // /512
    s = (wi == 0) ? Wq : (wi == 1) ? Wk : (wi == 2) ? Wv : Wo;
    d = WALL + (size_t)wi * WEc;
    base = (size_t)((bi - 12288) & 511) * 2048;
  }
  const size_t o = base + (size_t)threadIdx.x * 8;
  f32x4 lo = *(const f32x4*)(s + o);
  f32x4 hi = *(const f32x4*)(s + o + 4);
  *(u16x8*)(d + o) = cvt8(lo, hi);
}

// mask int32 -> bitmask (standalone, for NEED1 path)
__global__ __launch_bounds__(256)
void pack_mask(const int* __restrict__ m, unsigned long long* __restrict__ bits) {
  const size_t tid = (size_t)blockIdx.x * 256 + threadIdx.x;
  const unsigned long long bal = __ballot(m[tid] != 0);
  if ((threadIdx.x & 63) == 0) bits[tid >> 6] = bal;
}

// ---------------------------------------------------------------------------
// 8-PHASE 256x256 GEMM, 3-DEEP COUNTED-vmcnt pipeline (round-8, verified).
// + XCD-aware tile swizzle (T1): nwg per z = 128 (%8==0, bijective remap) so
// each XCD's blocks share one B-panel column (L2 reuse).
// ---------------------------------------------------------------------------
template <bool CF32>
DEVI void gemm8_body(const unsigned short* __restrict__ A,
                     const unsigned short* __restrict__ W,
                     void* __restrict__ Cp, int M, int N, int K, char* Lds,
                     int bm, int bn) {
  const int t = threadIdx.x;           // 0..511
  const int w = t >> 6, l = t & 63;
  const int lm = l & 15, lg = l >> 4;
  const int wm = (w >> 2) * 128;       // wave M base (0,128)
  const int wn = (w & 3) * 64;         // wave N base (0,64,128,192)

  const int sr8 = l >> 3;
  const int scol = ((l & 7) ^ sr8) * 8;
  const unsigned short* gA00 = A + (size_t)(bm +       w * 16 +     sr8) * K + scol;
  const unsigned short* gA01 = A + (size_t)(bm +       w * 16 + 8 + sr8) * K + scol;
  const unsigned short* gA10 = A + (size_t)(bm + 128 + w * 16 +     sr8) * K + scol;
  const unsigned short* gA11 = A + (size_t)(bm + 128 + w * 16 + 8 + sr8) * K + scol;
  const unsigned short* gB00 = W + (size_t)(bn +       w * 16 +     sr8) * K + scol;
  const unsigned short* gB01 = W + (size_t)(bn +       w * 16 + 8 + sr8) * K + scol;
  const unsigned short* gB10 = W + (size_t)(bn + 128 + w * 16 +     sr8) * K + scol;
  const unsigned short* gB11 = W + (size_t)(bn + 128 + w * 16 + 8 + sr8) * K + scol;
  const int ldst = w * 2048 + l * 16;

  auto stage2 = [&](int buf, int half, const unsigned short* g0,
                    const unsigned short* g1, int kofs) {
    char* p = Lds + buf * 65536 + half * 16384 + ldst;
    async16(p,        g0 + kofs);
    async16(p + 1024, g1 + kofs);
  };
  auto rdA = [&](int buf, int row, int ks) -> bf16x8 {
    const char* p = Lds + buf * 65536 + (row >> 7) * 16384 + (row & 127) * 128 +
                    ((ks * 64 + lg * 16) ^ ((row & 7) << 4));
    return *(const bf16x8*)p;
  };
  auto rdB = [&](int buf, int row, int ks) -> bf16x8 {
    const char* p = Lds + 32768 + buf * 65536 + (row >> 7) * 16384 +
                    (row & 127) * 128 + ((ks * 64 + lg * 16) ^ ((row & 7) << 4));
    return *(const bf16x8*)p;
  };

  f32x4 acc[8][4] = {};
  const int NT = K >> 6;

  stage2(0, 0, gA00, gA01, 0);
  stage2(0, 2, gB00, gB01, 0);
  stage2(0, 3, gB10, gB11, 0);
  stage2(0, 1, gA10, gA11, 0);
  if (NT > 1) {
    stage2(1, 0, gA00, gA01, 64);
    stage2(1, 2, gB00, gB01, 64);
    asm volatile("s_waitcnt vmcnt(4)" ::: "memory");
  } else {
    asm volatile("s_waitcnt vmcnt(0)" ::: "memory");
  }
  __builtin_amdgcn_sched_barrier(0);
  __builtin_amdgcn_s_barrier();

  for (int tt = 0; tt < NT; tt++) {
    const int cur = tt & 1, nxt = cur ^ 1;
    const bool p1 = (tt + 1 < NT), p2 = (tt + 2 < NT);
    const int ko1 = (tt + 1) * 64, ko2 = (tt + 2) * 64;
    bf16x8 aF[4][2], bF0[2][2], bF1[2][2];

#pragma unroll
    for (int mf = 0; mf < 4; mf++)
#pragma unroll
      for (int ks = 0; ks < 2; ks++)
        aF[mf][ks] = rdA(cur, wm + mf * 16 + lm, ks);
#pragma unroll
    for (int nf = 0; nf < 2; nf++)
#pragma unroll
      for (int ks = 0; ks < 2; ks++)
        bF0[nf][ks] = rdB(cur, wn + nf * 16 + lm, ks);
    if (p1) { stage2(nxt, 3, gB10, gB11, ko1); stage2(nxt, 1, gA10, gA11, ko1); }
    __builtin_amdgcn_s_barrier();
    asm volatile("s_waitcnt lgkmcnt(0)" ::: "memory");
    __builtin_amdgcn_sched_barrier(0);
    __builtin_amdgcn_s_setprio(1);
#pragma unroll
    for (int ks = 0; ks < 2; ks++)
#pragma unroll
      for (int mf = 0; mf < 4; mf++)
#pragma unroll
        for (int nf = 0; nf < 2; nf++)
          acc[mf][nf] = __builtin_amdgcn_mfma_f32_16x16x32_bf16(
              aF[mf][ks], bF0[nf][ks], acc[mf][nf], 0, 0, 0);
    __builtin_amdgcn_s_setprio(0);
    __builtin_amdgcn_s_barrier();

#pragma unroll
    for (int nf = 0; nf < 2; nf++)
#pragma unroll
      for (int ks = 0; ks < 2; ks++)
        bF1[nf][ks] = rdB(cur, wn + (nf + 2) * 16 + lm, ks);
    __builtin_amdgcn_s_barrier();
    asm volatile("s_waitcnt lgkmcnt(0)" ::: "memory");
    __builtin_amdgcn_sched_barrier(0);
    __builtin_amdgcn_s_setprio(1);
#pragma unroll
    for (int ks = 0; ks < 2; ks++)
#pragma unroll
      for (int mf = 0; mf < 4; mf++)
#pragma unroll
        for (int nf = 0; nf < 2; nf++)
          acc[mf][nf + 2] = __builtin_amdgcn_mfma_f32_16x16x32_bf16(
              aF[mf][ks], bF1[nf][ks], acc[mf][nf + 2], 0, 0, 0);
    __builtin_amdgcn_s_setprio(0);
    __builtin_amdgcn_s_barrier();

#pragma unroll
    for (int mf = 0; mf < 4; mf++)
#pragma unroll
      for (int ks = 0; ks < 2; ks++)
        aF[mf][ks] = rdA(cur, wm + (mf + 4) * 16 + lm, ks);
    __builtin_amdgcn_s_barrier();
    asm volatile("s_waitcnt lgkmcnt(0)" ::: "memory");
    __builtin_amdgcn_sched_barrier(0);
    __builtin_amdgcn_s_setprio(1);
#pragma unroll
    for (int ks = 0; ks < 2; ks++)
#pragma unroll
      for (int mf = 0; mf < 4; mf++)
#pragma unroll
        for (int nf = 0; nf < 2; nf++)
          acc[mf + 4][nf + 2] = __builtin_amdgcn_mfma_f32_16x16x32_bf16(
              aF[mf][ks], bF1[nf][ks], acc[mf + 4][nf + 2], 0, 0, 0);
    __builtin_amdgcn_s_setprio(0);
    __builtin_amdgcn_s_barrier();
    __builtin_amdgcn_sched_barrier(0);

    if (p2) { stage2(cur, 0, gA00, gA01, ko2); stage2(cur, 2, gB00, gB01, ko2); }
    __builtin_amdgcn_s_setprio(1);
#pragma unroll
    for (int ks = 0; ks < 2; ks++)
#pragma unroll
      for (int mf = 0; mf < 4; mf++)
#pragma unroll
        for (int nf = 0; nf < 2; nf++)
          acc[mf + 4][nf] = __builtin_amdgcn_mfma_f32_16x16x32_bf16(
              aF[mf][ks], bF0[nf][ks], acc[mf + 4][nf], 0, 0, 0);
    __builtin_amdgcn_s_setprio(0);

    if (p2)      { asm volatile("s_waitcnt vmcnt(4)" ::: "memory"); }
    else if (p1) { asm volatile("s_waitcnt vmcnt(0)" ::: "memory"); }
    __builtin_amdgcn_sched_barrier(0);
    __builtin_amdgcn_s_barrier();
  }

#pragma unroll
  for (int mf = 0; mf < 8; mf++)
#pragma unroll
    for (int nf = 0; nf < 4; nf++) {
      const int row = bm + wm + mf * 16 + lg * 4;
      const int col = bn + wn + nf * 16 + lm;
#pragma unroll
      for (int r = 0; r < 4; r++) {
        if constexpr (CF32) {
          ((float*)Cp)[(size_t)(row + r) * N + col] = acc[mf][nf][r];
        } else {
          ((unsigned short*)Cp)[(size_t)(row + r) * N + col] = f2bf_hu(acc[mf][nf][r]);
        }
      }
    }
}

// bijective XCD remap: nwg = gridDim.x*gridDim.y must be %8==0 (128 here)
DEVI void xcd_tile(int& bm, int& bn) {
  const int gx = gridDim.x;
  const int lin = blockIdx.x + gx * blockIdx.y;
  const int q = (gx * gridDim.y) >> 3;
  const int sw = (lin & 7) * q + (lin >> 3);
  bm = (sw % gx) * 256;
  bn = (sw / gx) * 256;
}

template <bool CF32>
__global__ __launch_bounds__(512)
void gemm8(const unsigned short* __restrict__ A, const unsigned short* __restrict__ W,
           void* __restrict__ Cp, int M, int N, int K) {
  __shared__ __align__(16) char Lds[131072];
  int bm, bn; xcd_tile(bm, bn);
  gemm8_body<CF32>(A, W, Cp, M, N, K, Lds, bm, bn);
}

__global__ __launch_bounds__(512)
void gemm8_qkv(const unsigned short* __restrict__ ACT,
               const unsigned short* __restrict__ WALL,
               unsigned short* __restrict__ Qb, unsigned short* __restrict__ Kb,
               unsigned short* __restrict__ Vb, int M, int N, int K) {
  __shared__ __align__(16) char Lds[131072];
  const int z = blockIdx.z;
  const unsigned short* A = ACT + (size_t)z * (size_t)M * (size_t)K;
  const unsigned short* W = WALL + (size_t)z * (size_t)N * (size_t)K;
  unsigned short* C = (z == 0) ? Qb : ((z == 1) ? Kb : Vb);
  int bm, bn; xcd_tile(bm, bn);
  gemm8_body<false>(A, W, (void*)C, M, N, K, Lds, bm, bn);
}

// ---------------------------------------------------------------------------
// 128x128 GEMM (kept for NEED1 path).
// ---------------------------------------------------------------------------
template <bool CF32>
DEVI void gemm_body_pipe(const unsigned short* __restrict__ A,
                         const unsigned short* __restrict__ Wb,
                         void* __restrict__ Cp, int M, int N, int K,
                         unsigned short* As, unsigned short* Bs) {
  const int t = threadIdx.x;
  const int w = t >> 6, l = t & 63;
  const int lm = l & 15, lg = l >> 4;
  const int bm = blockIdx.x * 128, bn = blockIdx.y * 128;
  const int wm = (w >> 1) * 64, wn = (w & 1) * 64;
  const int sr = t >> 2;
  const int sg = ((t & 3) ^ ((t >> 3) & 3)) * 8;
  const unsigned short* Ag0 = A + (size_t)(bm + sr) * K + sg;
  const unsigned short* Ag1 = A + (size_t)(bm + sr + 64) * K + sg;
  const unsigned short* Wg0 = Wb + (size_t)(bn + sr) * K + sg;
  const unsigned short* Wg1 = Wb + (size_t)(bn + sr + 64) * K + sg;
  const int fx = (lm >> 1) & 3;
  f32x4 acc[4][4] = {};
  auto stage = [&](int bi, int k0) {
    unsigned short* la = As + bi * 4096 + t * 8;
    unsigned short* lb = Bs + bi * 4096 + t * 8;
    async16(la,        Ag0 + k0);
    async16(la + 2048, Ag1 + k0);
    async16(lb,        Wg0 + k0);
    async16(lb + 2048, Wg1 + k0);
  };
  stage(0, 0);
  int cur = 0;
  for (int k0 = 0; k0 < K; k0 += 32) {
    if (k0 + 32 < K) {
      stage(cur ^ 1, k0 + 32);
      asm volatile("s_waitcnt vmcnt(4)" ::: "memory");
    } else {
      asm volatile("s_waitcnt vmcnt(0)" ::: "memory");
    }
    __builtin_amdgcn_sched_barrier(0);
    __builtin_amdgcn_s_barrier();
    const unsigned short* Ab = As + cur * 4096;
    const unsigned short* Bb = Bs + cur * 4096;
    bf16x8 aF[4], bF[4];
#pragma unroll
    for (int i = 0; i < 4; i++)
      aF[i] = *(const bf16x8*)&Ab[(wm + i * 16 + lm) * 32 + ((lg ^ fx) * 8)];
#pragma unroll
    for (int i = 0; i < 4; i++)
      bF[i] = *(const bf16x8*)&Bb[(wn + i * 16 + lm) * 32 + ((lg ^ fx) * 8)];
    __builtin_amdgcn_s_setprio(1);
#pragma unroll
    for (int i = 0; i < 4; i++)
#pragma unroll
      for (int j = 0; j < 4; j++)
        acc[i][j] = __builtin_amdgcn_mfma_f32_16x16x32_bf16(aF[i], bF[j], acc[i][j], 0, 0, 0);
    __builtin_amdgcn_s_setprio(0);
    __builtin_amdgcn_s_barrier();
    cur ^= 1;
  }
#pragma unroll
  for (int i = 0; i < 4; i++)
#pragma unroll
    for (int j = 0; j < 4; j++) {
      const int row = bm + wm + i * 16 + lg * 4;
      const int col = bn + wn + j * 16 + lm;
#pragma unroll
      for (int r = 0; r < 4; r++) {
        if constexpr (CF32) {
          ((float*)Cp)[(size_t)(row + r) * N + col] = acc[i][j][r];
        } else {
          ((unsigned short*)Cp)[(size_t)(row + r) * N + col] = f2bf_hu(acc[i][j][r]);
        }
      }
    }
}

template <bool CF32>
__global__ __launch_bounds__(256)
void gemm_bb(const unsigned short* __restrict__ A, const unsigned short* __restrict__ Wb,
             void* __restrict__ Cp, int M, int N, int K) {
  __shared__ unsigned short As[2 * 128 * 32];
  __shared__ unsigned short Bs[2 * 128 * 32];
  gemm_body_pipe<CF32>(A, Wb, Cp, M, N, K, As, Bs);
}

// ---------------------------------------------------------------------------
// FALLBACK GEMM: fp32 inputs, cvt-on-stage, register prefetch.
// ---------------------------------------------------------------------------
template <bool ABF16, bool CF32>
__global__ __launch_bounds__(256)
void gemm_bt(const void* __restrict__ Ap, const float* __restrict__ W,
             void* __restrict__ Cp, int M, int N, int K) {
  __shared__ unsigned short As[128 * 40];
  __shared__ unsigned short Bs[128 * 40];
  const int t = threadIdx.x;
  const int w = t >> 6, l = t & 63;
  const int lm = l & 15, lg = l >> 4;
  const int bm = blockIdx.x * 128, bn = blockIdx.y * 128;
  const int wm = (w >> 1) * 64, wn = (w & 1) * 64;
  const int sr = t >> 2, sc = (t & 3) * 8;
  const float* Af = (const float*)Ap;
  const unsigned short* Ab = (const unsigned short*)Ap;
  const size_t ao0 = (size_t)(bm + sr) * K + sc;
  const size_t ao1 = (size_t)(bm + sr + 64) * K + sc;
  const size_t wo0 = (size_t)(bn + sr) * K + sc;
  const size_t wo1 = (size_t)(bn + sr + 64) * K + sc;
  auto loadA = [&](size_t off) -> u16x8 {
    if constexpr (ABF16) {
      return *(const u16x8*)(Ab + off);
    } else {
      f32x4 lo = *(const f32x4*)(Af + off);
      f32x4 hi = *(const f32x4*)(Af + off + 4);
      return cvt8(lo, hi);
    }
  };
  auto loadW = [&](size_t off) -> u16x8 {
    f32x4 lo = *(const f32x4*)(W + off);
    f32x4 hi = *(const f32x4*)(W + off + 4);
    return cvt8(lo, hi);
  };
  u16x8 pa0 = loadA(ao0), pa1 = loadA(ao1);
  u16x8 pb0 = loadW(wo0), pb1 = loadW(wo1);
  f32x4 acc[4][4] = {};
  for (int k0 = 0; k0 < K; k0 += 32) {
    *(u16x8*)&As[sr * 40 + sc]        = pa0;
    *(u16x8*)&As[(sr + 64) * 40 + sc] = pa1;
    *(u16x8*)&Bs[sr * 40 + sc]        = pb0;
    *(u16x8*)&Bs[(sr + 64) * 40 + sc] = pb1;
    __syncthreads();
    if (k0 + 32 < K) {
      pa0 = loadA(ao0 + k0 + 32);
      pa1 = loadA(ao1 + k0 + 32);
      pb0 = loadW(wo0 + k0 + 32);
      pb1 = loadW(wo1 + k0 + 32);
    }
    bf16x8 aF[4], bF[4];
#pragma unroll
    for (int i = 0; i < 4; i++)
      aF[i] = *(const bf16x8*)&As[(wm + i * 16 + lm) * 40 + lg * 8];
#pragma unroll
    for (int i = 0; i < 4; i++)
      bF[i] = *(const bf16x8*)&Bs[(wn + i * 16 + lm) * 40 + lg * 8];
#pragma unroll
    for (int i = 0; i < 4; i++)
#pragma unroll
      for (int j = 0; j < 4; j++)
        acc[i][j] = __builtin_amdgcn_mfma_f32_16x16x32_bf16(aF[i], bF[j], acc[i][j], 0, 0, 0);
    __syncthreads();
  }
#pragma unroll
  for (int i = 0; i < 4; i++)
#pragma unroll
    for (int j = 0; j < 4; j++) {
      const int row = bm + wm + i * 16 + lg * 4;
      const int col = bn + wn + j * 16 + lm;
#pragma unroll
      for (int r = 0; r < 4; r++) {
        if constexpr (CF32) {
          ((float*)Cp)[(size_t)(row + r) * N + col] = acc[i][j][r];
        } else {
          ((unsigned short*)Cp)[(size_t)(row + r) * N + col] = f2bf_hu(acc[i][j][r]);
        }
      }
    }
}

// ---------------------------------------------------------------------------
// OLD SparseNormer attention (kept for NEED1/fallback paths). MODE 0/1.
// ---------------------------------------------------------------------------
template <int MODE>
__global__ __launch_bounds__(256)
void attn_sn(const unsigned short* __restrict__ Qb,
             const unsigned short* __restrict__ Kb,
             const unsigned short* __restrict__ Vb,
             const int* __restrict__ mask,
             const unsigned int* __restrict__ bits,
             const float* __restrict__ snb,
             unsigned short* __restrict__ Ob) {
  __shared__ unsigned short Ks[64 * 64];
  __shared__ unsigned short Vt[64 * 64];
  __shared__ unsigned short Pq[128 * 64];

  const int h = blockIdx.x, qt = blockIdx.y, b = blockIdx.z;
  const int t = threadIdx.x, w = t >> 6, l = t & 63;
  const int lm = l & 15, lg = l >> 4;
  const int q0 = qt * 128;
  const int wk = (w >> 1) * 32;
  const int wn = (w & 1) * 64;
  const float bias = snb[0];

  char* KsB = (char*)Ks;
  char* VtB = (char*)Vt;
  char* PqB = (char*)Pq;

  bf16x8 bQ[4][2];
#pragma unroll
  for (int ni = 0; ni < 4; ni++)
#pragma unroll
    for (int kf = 0; kf < 2; kf++) {
      const int qq = q0 + wn + ni * 16 + lm;
      bQ[ni][kf] = *(const bf16x8*)&Qb[(size_t)(b * NQ_ + qq) * HS_ + h * D_ + kf * 32 + lg * 8];
    }

  const int kr = t >> 3, kcb = (t & 7) * 16;
  const unsigned short* Kg = Kb + (size_t)(b * SK_) * HS_ + h * D_ + (t & 7) * 8;
  const int va = t & 31;
  const int vc = (t >> 5) * 8;
  const unsigned short* Vg = Vb + (size_t)(b * SK_) * HS_ + h * D_ + vc;
  const int* mbase = mask + (size_t)b * NQ_ * SK_;

  f32x4 oacc[2][4] = {};
  float dpart[4] = {0.f, 0.f, 0.f, 0.f};
  f32x2 dp2[4] = {};

  u16x8 pk0 = *(const u16x8*)(Kg + (size_t)(kr) * HS_);
  u16x8 pk1 = *(const u16x8*)(Kg + (size_t)(32 + kr) * HS_);
  u16x8 pv0 = *(const u16x8*)(Vg + (size_t)(2 * va) * HS_);
  u16x8 pv1 = *(const u16x8*)(Vg + (size_t)(2 * va + 1) * HS_);

  for (int kt = 0; kt < SK_ / 64; kt++) {
    const int kk0 = kt * 64;
    *(u16x8*)(KsB + SWZB(kr, kcb))      = pk0;
    *(u16x8*)(KsB + SWZB(kr + 32, kcb)) = pk1;
    {
      union { u16x8 s; unsigned int w4[4]; } a0, a1;
      a0.s = pv0; a1.s = pv1;
#pragma unroll
      for (int ww = 0; ww < 4; ww++) {
        unsigned int lo = __builtin_amdgcn_perm(a1.w4[ww], a0.w4[ww], 0x05040100u);
        unsigned int hi = __builtin_amdgcn_perm(a1.w4[ww], a0.w4[ww], 0x07060302u);
        *(unsigned int*)(VtB + SWZB(vc + 2 * ww,     4 * va)) = lo;
        *(unsigned int*)(VtB + SWZB(vc + 2 * ww + 1, 4 * va)) = hi;
      }
    }
    __syncthreads();

    if (kt + 1 < SK_ / 64) {
      const int nk0 = kk0 + 64;
      pk0 = *(const u16x8*)(Kg + (size_t)(nk0 + kr) * HS_);
      pk1 = *(const u16x8*)(Kg + (size_t)(nk0 + 32 + kr) * HS_);
      pv0 = *(const u16x8*)(Vg + (size_t)(nk0 + 2 * va) * HS_);
      pv1 = *(const u16x8*)(Vg + (size_t)(nk0 + 2 * va + 1) * HS_);
    }

    i32x4 mq[4][2];
    unsigned int mb[4];
    if constexpr (MODE == 1) {
#pragma unroll
      for (int ni = 0; ni < 4; ni++)
        mb[ni] = bits[(size_t)(b * NQ_ + q0 + wn + ni * 16 + lm) * 64 + kt * 2 + (wk >> 5)];
    } else {
#pragma unroll
      for (int ni = 0; ni < 4; ni++) {
        const int* mrow = mbase + (size_t)(q0 + wn + ni * 16 + lm) * SK_ + kk0 + wk + lg * 4;
#pragma unroll
        for (int mi = 0; mi < 2; mi++) mq[ni][mi] = *(const i32x4*)(mrow + mi * 16);
      }
    }

    bf16x8 aK[2][2];
#pragma unroll
    for (int mi = 0; mi < 2; mi++)
#pragma unroll
      for (int kf = 0; kf < 2; kf++)
        aK[mi][kf] = *(const bf16x8*)(KsB + SWZB(wk + mi * 16 + lm, kf * 64 + lg * 16));
    f32x4 sf[2][4] = {};
    __builtin_amdgcn_s_setprio(1);
#pragma unroll
    for (int mi = 0; mi < 2; mi++)
#pragma unroll
      for (int ni = 0; ni < 4; ni++) {
        sf[mi][ni] = __builtin_amdgcn_mfma_f32_16x16x32_bf16(aK[mi][0], bQ[ni][0], sf[mi][ni], 0, 0, 0);
        sf[mi][ni] = __builtin_amdgcn_mfma_f32_16x16x32_bf16(aK[mi][1], bQ[ni][1], sf[mi][ni], 0, 0, 0);
      }
    __builtin_amdgcn_s_setprio(0);

    if constexpr (MODE == 1) {
      const f32x2 c8 = {0.125f, 0.125f};
      const f32x2 bias2 = {bias, bias};
#pragma unroll
      for (int ni = 0; ni < 4; ni++) {
        const unsigned int nb = (~mb[ni]) >> (lg * 4);
#pragma unroll
        for (int mi = 0; mi < 2; mi++) {
          const f32x4 sv = sf[mi][ni];
          f32x2 t01 = pkfma((f32x2){sv[0], sv[1]}, c8, bias2);
          f32x2 t23 = pkfma((f32x2){sv[2], sv[3]}, c8, bias2);
          float x0 = fmaxf(t01[0], 0.f), x1 = fmaxf(t01[1], 0.f);
          float x2 = fmaxf(t23[0], 0.f), x3 = fmaxf(t23[1], 0.f);
          if (mi == 0) {
            x0 = keepf<0>(x0, nb);  x1 = keepf<1>(x1, nb);
            x2 = keepf<2>(x2, nb);  x3 = keepf<3>(x3, nb);
          } else {
            x0 = keepf<16>(x0, nb); x1 = keepf<17>(x1, nb);
            x2 = keepf<18>(x2, nb); x3 = keepf<19>(x3, nb);
          }
          const f32x2 u01 = pkmul((f32x2){x0, x1}, (f32x2){x0, x1});
          const f32x2 u23 = pkmul((f32x2){x2, x3}, (f32x2){x2, x3});
          dp2[ni] = pkadd(dp2[ni], u01);
          dp2[ni] = pkadd(dp2[ni], u23);
          const unsigned long long pk =
              (unsigned long long)cvtpk_bf16(u01[0], u01[1]) |
              ((unsigned long long)cvtpk_bf16(u23[0], u23[1]) << 32);
          *(unsigned long long*)(PqB + SWZB(wn + ni * 16 + lm, (wk + mi * 16 + lg * 4) * 2)) = pk;
        }
      }
    } else {
#pragma unroll
      for (int ni = 0; ni < 4; ni++) {
        float dsum = 0.f;
#pragma unroll
        for (int mi = 0; mi < 2; mi++) {
          const f32x4 sv = sf[mi][ni];
          float x2[4];
#pragma unroll
          for (int r = 0; r < 4; r++) {
            float x = fmaxf(sv[r] * 0.125f + bias, 0.f);
            x = mq[ni][mi][r] ? 0.f : x;
            x2[r] = x * x;
            dsum += x2[r];
          }
          const unsigned long long pk =
              (unsigned long long)pack2(x2[0], x2[1]) |
              ((unsigned long long)pack2(x2[2], x2[3]) << 32);
          *(unsigned long long*)(PqB + SWZB(wn + ni * 16 + lm, (wk + mi * 16 + lg * 4) * 2)) = pk;
        }
        dpart[ni] += dsum;
      }
    }
    __syncthreads();

#pragma unroll
    for (int k2 = 0; k2 < 2; k2++) {
      bf16x8 aV[2], bP[4];
#pragma unroll
      for (int mi = 0; mi < 2; mi++)
        aV[mi] = *(const bf16x8*)(VtB + SWZB(wk + mi * 16 + lm, k2 * 64 + lg * 16));
#pragma unroll
      for (int ni = 0; ni < 4; ni++)
        bP[ni] = *(const bf16x8*)(PqB + SWZB(wn + ni * 16 + lm, k2 * 64 + lg * 16));
      __builtin_amdgcn_s_setprio(1);
#pragma unroll
      for (int mi = 0; mi < 2; mi++)
#pragma unroll
        for (int ni = 0; ni < 4; ni++)
          oacc[mi][ni] = __builtin_amdgcn_mfma_f32_16x16x32_bf16(aV[mi], bP[ni], oacc[mi][ni], 0, 0, 0);
      __builtin_amdgcn_s_setprio(0);
    }
    __syncthreads();
  }

  float* denomS = (float*)Ks;
#pragma unroll
  for (int ni = 0; ni < 4; ni++) {
    float v = (MODE == 1) ? (dp2[ni][0] + dp2[ni][1]) : dpart[ni];
    v += __shfl_xor(v, 16, 64);
    v += __shfl_xor(v, 32, 64);
    dpart[ni] = v;
  }
  if (((w >> 1) == 0) && (lg == 0)) {
#pragma unroll
    for (int ni = 0; ni < 4; ni++) denomS[wn + ni * 16 + lm] = dpart[ni];
  }
  __syncthreads();
  if (((w >> 1) == 1) && (lg == 0)) {
#pragma unroll
    for (int ni = 0; ni < 4; ni++) denomS[wn + ni * 16 + lm] += dpart[ni];
  }
  __syncthreads();

#pragma unroll
  for (int ni = 0; ni < 4; ni++) {
    const int ql = wn + ni * 16 + lm;
    const float inv = 1.0f / (denomS[ql] + 1e-32f);
#pragma unroll
    for (int mi = 0; mi < 2; mi++) {
      const int d0 = wk + mi * 16 + lg * 4;
      const f32x4 ov = oacc[mi][ni];
      const unsigned long long pk =
          (unsigned long long)cvtpk_bf16(ov[0] * inv, ov[1] * inv) |
          ((unsigned long long)cvtpk_bf16(ov[2] * inv, ov[3] * inv) << 32);
      *(unsigned long long*)(PqB + SWZB(ql, d0 * 2)) = pk;
    }
  }
  __syncthreads();
  const int qf = t >> 1;
  unsigned short* orow = Ob + (size_t)(b * NQ_ + q0 + qf) * HS_ + h * D_ + (t & 1) * 32;
#pragma unroll
  for (int j = 0; j < 4; j++) {
    u16x8 vv = *(const u16x8*)(PqB + SWZB(qf, (t & 1) * 64 + j * 16));
    *(u16x8*)(orow + j * 8) = vv;
  }
}

// ---------------------------------------------------------------------------
// NEW attention (fast path): software-pipelined by one K-tile (T15).
// At iteration t: QK(t+1) MFMAs (into sfN, from double-buffered Ks) run in the
// SAME scheduling region as softmax(t) VALU (from sfC) -> MFMA issue hides
// under the serial VALU chain. Bias folded into the QK accumulator C-init
// (relu(s/8+b) = (1/8)relu(s+8b); SparseNormer is scale-invariant, so the
// 1/64 on P and denom cancels exactly) -> pkfma dropped from softmax.
// sfA/sfB ping-pong via 2-step unrolled loop (no runtime indexing, rule #20).
// ---------------------------------------------------------------------------
__global__ __launch_bounds__(256)
void attn_sn2(const unsigned short* __restrict__ Qb,
              const unsigned short* __restrict__ Kb,
              const unsigned short* __restrict__ Vb,
              const unsigned int* __restrict__ bits,
              const float* __restrict__ snb,
              unsigned short* __restrict__ Ob) {
  __shared__ unsigned short Ks[2][64 * 64];  // 16 KB (double-buffered)
  __shared__ unsigned short Vt[64 * 64];     //  8 KB
  __shared__ unsigned short Pq[128 * 64];    // 16 KB

  const int h = blockIdx.x, qt = blockIdx.y, b = blockIdx.z;
  const int t = threadIdx.x, w = t >> 6, l = t & 63;
  const int lm = l & 15, lg = l >> 4;
  const int q0 = qt * 128;
  const int wk = (w >> 1) * 32;
  const int wn = (w & 1) * 64;
  const float b8 = snb[0] * 8.0f;

  char* KsB = (char*)Ks;
  char* VtB = (char*)Vt;
  char* PqB = (char*)Pq;

  bf16x8 bQ[4][2];
#pragma unroll
  for (int ni = 0; ni < 4; ni++)
#pragma unroll
    for (int kf = 0; kf < 2; kf++) {
      const int qq = q0 + wn + ni * 16 + lm;
      bQ[ni][kf] = *(const bf16x8*)&Qb[(size_t)(b * NQ_ + qq) * HS_ + h * D_ + kf * 32 + lg * 8];
    }

  const int kr = t >> 3, kcb = (t & 7) * 16;
  const unsigned short* Kg = Kb + (size_t)(b * SK_) * HS_ + h * D_ + (t & 7) * 8;
  const int va = t & 31;
  const int vc = (t >> 5) * 8;
  const unsigned short* Vg = Vb + (size_t)(b * SK_) * HS_ + h * D_ + vc;
  const size_t bitbase = (size_t)(b * NQ_ + q0 + wn + lm) * 64 + (wk >> 5);

  f32x4 oacc[2][4] = {};
  f32x2 dp2[4] = {};
  f32x4 sfA[2][4], sfB[2][4];
  unsigned int mbA[4], mbB[4];
  u16x8 pk0, pk1, pv0, pv1;

  // QK of tile `buf` into SN (C-init = 8*bias)
  auto qk_tile = [&](int buf, f32x4 (&SN)[2][4]) {
    bf16x8 aK[2][2];
#pragma unroll
    for (int mi = 0; mi < 2; mi++)
#pragma unroll
      for (int kf = 0; kf < 2; kf++)
        aK[mi][kf] = *(const bf16x8*)(KsB + buf * 8192 +
                                      SWZB(wk + mi * 16 + lm, kf * 64 + lg * 16));
#pragma unroll
    for (int mi = 0; mi < 2; mi++)
#pragma unroll
      for (int ni = 0; ni < 4; ni++) {
        SN[mi][ni] = (f32x4){b8, b8, b8, b8};
        SN[mi][ni] = __builtin_amdgcn_mfma_f32_16x16x32_bf16(aK[mi][0], bQ[ni][0], SN[mi][ni], 0, 0, 0);
        SN[mi][ni] = __builtin_amdgcn_mfma_f32_16x16x32_bf16(aK[mi][1], bQ[ni][1], SN[mi][ni], 0, 0, 0);
      }
  };

  // softmax of SC (already includes +8b), mask MC -> Pq, dp2
  auto softmax = [&](f32x4 (&SC)[2][4], unsigned int (&MC)[4]) {
#pragma unroll
    for (int ni = 0; ni < 4; ni++) {
      const unsigned int nb = (~MC[ni]) >> (lg * 4);
#pragma unroll
      for (int mi = 0; mi < 2; mi++) {
        const f32x4 sv = SC[mi][ni];
        float x0 = fmaxf(sv[0], 0.f), x1 = fmaxf(sv[1], 0.f);
        float x2 = fmaxf(sv[2], 0.f), x3 = fmaxf(sv[3], 0.f);
        if (mi == 0) {
          x0 = keepf<0>(x0, nb);  x1 = keepf<1>(x1, nb);
          x2 = keepf<2>(x2, nb);  x3 = keepf<3>(x3, nb);
        } else {
          x0 = keepf<16>(x0, nb); x1 = keepf<17>(x1, nb);
          x2 = keepf<18>(x2, nb); x3 = keepf<19>(x3, nb);
        }
        const f32x2 u01 = pkmul((f32x2){x0, x1}, (f32x2){x0, x1});
        const f32x2 u23 = pkmul((f32x2){x2, x3}, (f32x2){x2, x3});
        dp2[ni] = pkadd(dp2[ni], u01);
        dp2[ni] = pkadd(dp2[ni], u23);
        const unsigned long long pk =
            (unsigned long long)cvtpk_bf16(u01[0], u01[1]) |
            ((unsigned long long)cvtpk_bf16(u23[0], u23[1]) << 32);
        *(unsigned long long*)(PqB + SWZB(wn + ni * 16 + lm, (wk + mi * 16 + lg * 4) * 2)) = pk;
      }
    }
  };

  // one pipelined iteration: consume (SC,MC) for tile kt; produce (SN,MN) for kt+1
  auto step = [&](int kt, f32x4 (&SC)[2][4], f32x4 (&SN)[2][4],
                  unsigned int (&MC)[4], unsigned int (&MN)[4]) {
    const bool more = (kt + 1 < SK_ / 64);
    const int nxtb = (kt + 1) & 1;
    // [A] stage K(kt+1) into Ks[nxtb]; transpose V(kt) into Vt
    if (more) {
      *(u16x8*)(KsB + nxtb * 8192 + SWZB(kr, kcb))      = pk0;
      *(u16x8*)(KsB + nxtb * 8192 + SWZB(kr + 32, kcb)) = pk1;
    }
    {
      union { u16x8 s; unsigned int w4[4]; } a0, a1;
      a0.s = pv0; a1.s = pv1;
#pragma unroll
      for (int ww = 0; ww < 4; ww++) {
        unsigned int lo = __builtin_amdgcn_perm(a1.w4[ww], a0.w4[ww], 0x05040100u);
        unsigned int hi = __builtin_amdgcn_perm(a1.w4[ww], a0.w4[ww], 0x07060302u);
        *(unsigned int*)(VtB + SWZB(vc + 2 * ww,     4 * va)) = lo;
        *(unsigned int*)(VtB + SWZB(vc + 2 * ww + 1, 4 * va)) = hi;
      }
    }
    __syncthreads();
    // [C] prefetch V(kt+1), mask(kt+1), K(kt+2)
    if (more) {
      const int nk = (kt + 1) * 64;
      pv0 = *(const u16x8*)(Vg + (size_t)(nk + 2 * va) * HS_);
      pv1 = *(const u16x8*)(Vg + (size_t)(nk + 2 * va + 1) * HS_);
#pragma unroll
      for (int ni = 0; ni < 4; ni++)
        MN[ni] = bits[bitbase + (size_t)ni * 16 * 64 + (kt + 1) * 2];
    }
    if (kt + 2 < SK_ / 64) {
      const int nk2 = (kt + 2) * 64;
      pk0 = *(const u16x8*)(Kg + (size_t)(nk2 + kr) * HS_);
      pk1 = *(const u16x8*)(Kg + (size_t)(nk2 + 32 + kr) * HS_);
    }
    // [D] QK(kt+1) MFMAs || softmax(kt) VALU — independent, co-scheduled
    if (more) qk_tile(nxtb, SN);
    softmax(SC, MC);
    __syncthreads();
    // [F] PV(kt)
#pragma unroll
    for (int k2 = 0; k2 < 2; k2++) {
      bf16x8 aV[2], bP[4];
#pragma unroll
      for (int mi = 0; mi < 2; mi++)
        aV[mi] = *(const bf16x8*)(VtB + SWZB(wk + mi * 16 + lm, k2 * 64 + lg * 16));
#pragma unroll
      for (int ni = 0; ni < 4; ni++)
        bP[ni] = *(const bf16x8*)(PqB + SWZB(wn + ni * 16 + lm, k2 * 64 + lg * 16));
      __builtin_amdgcn_s_setprio(1);
#pragma unroll
      for (int mi = 0; mi < 2; mi++)
#pragma unroll
        for (int ni = 0; ni < 4; ni++)
          oacc[mi][ni] = __builtin_amdgcn_mfma_f32_16x16x32_bf16(aV[mi], bP[ni], oacc[mi][ni], 0, 0, 0);
      __builtin_amdgcn_s_setprio(0);
    }
    __syncthreads();
  };

  // ---- prologue: stage K(0)->Ks[0]; V(0)->regs; QK(0)->sfA; K(1),mb(0) prefetch
  pk0 = *(const u16x8*)(Kg + (size_t)(kr) * HS_);
  pk1 = *(const u16x8*)(Kg + (size_t)(32 + kr) * HS_);
  *(u16x8*)(KsB + SWZB(kr, kcb))      = pk0;
  *(u16x8*)(KsB + SWZB(kr + 32, kcb)) = pk1;
  pv0 = *(const u16x8*)(Vg + (size_t)(2 * va) * HS_);
  pv1 = *(const u16x8*)(Vg + (size_t)(2 * va + 1) * HS_);
  __syncthreads();
  qk_tile(0, sfA);
  pk0 = *(const u16x8*)(Kg + (size_t)(64 + kr) * HS_);
  pk1 = *(const u16x8*)(Kg + (size_t)(64 + 32 + kr) * HS_);
#pragma unroll
  for (int ni = 0; ni < 4; ni++)
    mbA[ni] = bits[bitbase + (size_t)ni * 16 * 64];

  // ---- main loop (32 tiles, 2-step unroll for sfA/sfB ping-pong)
  for (int kt2 = 0; kt2 < SK_ / 64; kt2 += 2) {
    step(kt2,     sfA, sfB, mbA, mbB);
    step(kt2 + 1, sfB, sfA, mbB, mbA);
  }

  // ---- epilogue (denom reduce + normalize + store)
  float* denomS = (float*)Ks;  // Ks dead after final barrier
  float dpart[4];
#pragma unroll
  for (int ni = 0; ni < 4; ni++) {
    float v = dp2[ni][0] + dp2[ni][1];
    v += __shfl_xor(v, 16, 64);
    v += __shfl_xor(v, 32, 64);
    dpart[ni] = v;
  }
  if (((w >> 1) == 0) && (lg == 0)) {
#pragma unroll
    for (int ni = 0; ni < 4; ni++) denomS[wn + ni * 16 + lm] = dpart[ni];
  }
  __syncthreads();
  if (((w >> 1) == 1) && (lg == 0)) {
#pragma unroll
    for (int ni = 0; ni < 4; ni++) denomS[wn + ni * 16 + lm] += dpart[ni];
  }
  __syncthreads();

#pragma unroll
  for (int ni = 0; ni < 4; ni++) {
    const int ql = wn + ni * 16 + lm;
    const float inv = 1.0f / (denomS[ql] + 1e-32f);
#pragma unroll
    for (int mi = 0; mi < 2; mi++) {
      const int d0 = wk + mi * 16 + lg * 4;
      const f32x4 ov = oacc[mi][ni];
      const unsigned long long pk =
          (unsigned long long)cvtpk_bf16(ov[0] * inv, ov[1] * inv) |
          ((unsigned long long)cvtpk_bf16(ov[2] * inv, ov[3] * inv) << 32);
      *(unsigned long long*)(PqB + SWZB(ql, d0 * 2)) = pk;
    }
  }
  __syncthreads();
  const int qf = t >> 1;
  unsigned short* orow = Ob + (size_t)(b * NQ_ + q0 + qf) * HS_ + h * D_ + (t & 1) * 32;
#pragma unroll
  for (int j = 0; j < 4; j++) {
    u16x8 vv = *(const u16x8*)(PqB + SWZB(qf, (t & 1) * 64 + j * 16));
    *(u16x8*)(orow + j * 8) = vv;
  }
}

// ---------------------------------------------------------------------------
extern "C" void kernel_launch(void* const* d_in, const int* in_sizes, int n_in,
                              void* d_out, int out_size, void* d_ws, size_t ws_size,
                              hipStream_t stream) {
  (void)in_sizes; (void)n_in; (void)out_size;
  const float* iQ  = (const float*)d_in[0];
  const float* iK  = (const float*)d_in[1];
  const float* iV  = (const float*)d_in[2];
  const int*   msk = (const int*)d_in[3];
  const float* Wq  = (const float*)d_in[4];
  const float* Wk  = (const float*)d_in[5];
  const float* Wv  = (const float*)d_in[6];
  const float* Wo  = (const float*)d_in[7];
  const float* snb = (const float*)d_in[8];
  float* out = (float*)d_out;

  const size_t TOK = TOKc;                             // 8.39M elems
  const size_t WE  = WEc;                              // 1.05M elems
  const size_t BITS_B = (size_t)B_ * NQ_ * SK_ / 8;    // 2.10 MB
  const size_t NEED1 = (3 * TOK + WE) * 2 + BITS_B;    // 54.5 MB
  const size_t NEEDF = (6 * TOK + 4 * WE) * 2 + BITS_B;// 111.1 MB

  const dim3 gg(64, 8, 1), bb(256, 1, 1);
  const dim3 ga(H_, NQ_ / 128, B_);
  const dim3 g8(32, 4, 1), g83(32, 4, 3), b512(512, 1, 1);
  const int M = B_ * NQ_, N = HS_, K = HS_;

  if (ws_size >= NEEDF) {
    // --- fused fast path: one cvt+pack, qkv GEMM, pipelined attn, O GEMM
    unsigned short* ACT  = (unsigned short*)d_ws;  // 3*TOK bf16 (iQ,iK,iV)
    unsigned short* WALL = ACT + 3 * TOK;          // 4*WE bf16 (Wq,Wk,Wv,Wo)
    unsigned short* Kb   = WALL + 4 * WE;
    unsigned short* Vb   = Kb + TOK;
    unsigned short* Ob   = Vb + TOK;
    unsigned int*  bits  = (unsigned int*)(Ob + TOK);
    unsigned short* Qb   = (unsigned short*)d_out;  // dead before final GEMM
    unsigned short* Wob  = WALL + 3 * WE;

    hipLaunchKernelGGL(cvt_pack, dim3(79872), bb, 0, stream,
                       iQ, iK, iV, Wq, Wk, Wv, Wo, msk, ACT, WALL,
                       (unsigned long long*)bits);
    hipLaunchKernelGGL(gemm8_qkv, g83, b512, 0, stream,
                       ACT, WALL, Qb, Kb, Vb, M, N, K);
    hipLaunchKernelGGL(attn_sn2, ga, bb, 0, stream,
                       Qb, Kb, Vb, bits, snb, Ob);
    hipLaunchKernelGGL((gemm8<true>), g8, b512, 0, stream,
                       Ob, Wob, (void*)out, M, N, K);
  } else if (ws_size >= NEED1) {
    // --- round-0 path: per-tensor cvt + 128^2 GEMM, bitmask attn (old)
    unsigned short* Kb = (unsigned short*)d_ws;
    unsigned short* Vb = Kb + TOK;
    unsigned short* Ob = Vb + TOK;
    unsigned short* Wb = Ob + TOK;
    unsigned int* bits = (unsigned int*)(Wb + WE);
    unsigned short* out_us = (unsigned short*)d_out;
    unsigned short* Qb  = out_us;
    unsigned short* INb = out_us + TOK;

    hipLaunchKernelGGL(cvt_prep, dim3(4608), bb, 0, stream, iQ, INb, Wq, Wb, 4096);
    hipLaunchKernelGGL((gemm_bb<false>), gg, bb, 0, stream, INb, Wb, (void*)Qb, M, N, K);
    hipLaunchKernelGGL(cvt_prep, dim3(4608), bb, 0, stream, iK, INb, Wk, Wb, 4096);
    hipLaunchKernelGGL((gemm_bb<false>), gg, bb, 0, stream, INb, Wb, (void*)Kb, M, N, K);
    hipLaunchKernelGGL(cvt_prep, dim3(4608), bb, 0, stream, iV, INb, Wv, Wb, 4096);
    hipLaunchKernelGGL((gemm_bb<false>), gg, bb, 0, stream, INb, Wb, (void*)Vb, M, N, K);
    hipLaunchKernelGGL(cvt_prep, dim3(512), bb, 0, stream,
                       (const float*)nullptr, (unsigned short*)nullptr, Wo, Wb, 0);
    hipLaunchKernelGGL(pack_mask, dim3(65536), bb, 0, stream,
                       msk, (unsigned long long*)bits);
    hipLaunchKernelGGL((attn_sn<1>), ga, bb, 0, stream,
                       Qb, Kb, Vb, msk, bits, snb, Ob);
    hipLaunchKernelGGL((gemm_bb<true>), gg, bb, 0, stream, Ob, Wb, (void*)out, M, N, K);
  } else {
    // --- fallback: round-5 known-good path (needs only 50.3 MB ws)
    unsigned short *Qb, *Kb, *Vb, *Ob;
    if (ws_size >= 4 * TOK * sizeof(unsigned short)) {
      Qb = (unsigned short*)d_ws;
      Kb = Qb + TOK;
      Vb = Qb + 2 * TOK;
      Ob = Qb + 3 * TOK;
    } else {
      Qb = (unsigned short*)d_out;
      Kb = (unsigned short*)d_ws;
      Vb = Kb + TOK;
      Ob = Kb + 2 * TOK;
    }
    hipLaunchKernelGGL((gemm_bt<false, false>), gg, bb, 0, stream, (const void*)iQ, Wq, (void*)Qb, M, N, K);
    hipLaunchKernelGGL((gemm_bt<false, false>), gg, bb, 0, stream, (const void*)iK, Wk, (void*)Kb, M, N, K);
    hipLaunchKernelGGL((gemm_bt<false, false>), gg, bb, 0, stream, (const void*)iV, Wv, (void*)Vb, M, N, K);
    hipLaunchKernelGGL((attn_sn<0>), ga, bb, 0, stream,
                       Qb, Kb, Vb, msk, (const unsigned int*)nullptr, snb, Ob);
    hipLaunchKernelGGL((gemm_bt<true, true>), gg, bb, 0, stream, (const void*)Ob, Wo, (void*)out, M, N, K);
  }
}